// Round 15
// baseline (280.789 us; speedup 1.0000x reference)
//
#include <hip/hip_runtime.h>
#include <stdint.h>

typedef __attribute__((ext_vector_type(8))) short short8;
typedef __attribute__((ext_vector_type(4))) float f32x4;

static constexpr int D  = 1024;
static constexpr int H  = 16;
static constexpr int L  = 4096;
static constexpr int NB = 4;
static constexpr int M  = NB * L;      // 16384 rows
static constexpr int NP = 3 * H * 64;  // 3072 param cols
static constexpr int CHUNK = 512;      // B/C/delta guaranteed-compute prefix rows

__device__ __forceinline__ float bf2f(unsigned short u) {
    unsigned int v = ((unsigned int)u) << 16;
    return __builtin_bit_cast(float, v);
}
__device__ __forceinline__ unsigned short f2bf(float f) {
    unsigned int x = __builtin_bit_cast(unsigned int, f);
    x += 0x7fffu + ((x >> 16) & 1u);
    return (unsigned short)(x >> 16);
}
__device__ __forceinline__ float fsigmoid(float v) {
    return __builtin_amdgcn_rcpf(1.0f + __expf(-v));
}
__device__ __forceinline__ void async_lds16(void* lds, const void* g) {
    __builtin_amdgcn_global_load_lds(
        (const __attribute__((address_space(1))) unsigned int*)g,
        (__attribute__((address_space(3))) unsigned int*)lds,
        16, 0, 0);
}

// ---------------- prep: init flags + W4 cast + ow cast ---------------------
// W4 rows: [0,1024) gate gw | [1024,2048) B | [2048,3072) C | [3072,4096) delta
// blocks 4096..5119: owh rows.
__global__ __launch_bounds__(256) void prep_kernel(const float* __restrict__ gw,
                                                   const float* __restrict__ pw,
                                                   const float* __restrict__ ow,
                                                   unsigned short* __restrict__ w4,
                                                   unsigned short* __restrict__ owh,
                                                   int* __restrict__ need_tail) {
    if (blockIdx.x == 0 && threadIdx.x < NB) need_tail[threadIdx.x] = 0;
    const int rr = blockIdx.x;
    const float* src;
    unsigned short* dst;
    if (rr < 1024) {
        src = gw + (size_t)rr * 1024;
        dst = w4 + (size_t)rr * 1024;
    } else if (rr < 2048) {
        const int r = rr - 1024;
        src = pw + (size_t)((r >> 6) * 192 + 64 + (r & 63)) * 1024;
        dst = w4 + (size_t)rr * 1024;
    } else if (rr < 3072) {
        const int r = rr - 2048;
        src = pw + (size_t)((r >> 6) * 192 + 128 + (r & 63)) * 1024;
        dst = w4 + (size_t)rr * 1024;
    } else if (rr < 4096) {
        const int r = rr - 3072;
        src = pw + (size_t)((r >> 6) * 192 + (r & 63)) * 1024;
        dst = w4 + (size_t)rr * 1024;
    } else {
        const int r = rr - 4096;
        src = ow + (size_t)r * 1024;
        dst = owh + (size_t)r * 1024;
    }
    const int t = threadIdx.x * 4;
    const float4 v = *reinterpret_cast<const float4*>(src + t);
    ushort4 o;
    o.x = f2bf(v.x); o.y = f2bf(v.y); o.z = f2bf(v.z); o.w = f2bf(v.w);
    *reinterpret_cast<ushort4*>(dst + t) = o;
}

// ---------------- RMSNorm (fp32 in -> bf16 out) ----------------
__global__ __launch_bounds__(256) void rmsnorm_kernel(const float* __restrict__ x,
                                                      const float* __restrict__ w,
                                                      unsigned short* __restrict__ xn) {
    const int row = blockIdx.x;
    const int t = threadIdx.x;
    const float4 v = *reinterpret_cast<const float4*>(x + (size_t)row * D + t * 4);
    float s = v.x * v.x + v.y * v.y + v.z * v.z + v.w * v.w;
    #pragma unroll
    for (int o = 32; o > 0; o >>= 1) s += __shfl_down(s, o, 64);
    __shared__ float red[4];
    if ((t & 63) == 0) red[t >> 6] = s;
    __syncthreads();
    const float tot = red[0] + red[1] + red[2] + red[3];
    const float rinv = 1.0f / sqrtf(tot * (1.0f / D) + 1e-6f);
    const float4 wv = *reinterpret_cast<const float4*>(w + t * 4);
    ushort4 o;
    o.x = f2bf(wv.x * v.x * rinv);
    o.y = f2bf(wv.y * v.y * rinv);
    o.z = f2bf(wv.z * v.z * rinv);
    o.w = f2bf(wv.w * v.w * rinv);
    *reinterpret_cast<ushort4*>(xn + (size_t)row * D + t * 4) = o;
}

// ---------------- depthwise causal conv (K=4) + SiLU (bf16 -> bf16) --------
__global__ __launch_bounds__(256) void conv_silu_kernel(const unsigned short* __restrict__ xn,
                                                        const float* __restrict__ cw,
                                                        const float* __restrict__ cb,
                                                        unsigned short* __restrict__ xc) {
    const int row = blockIdx.x;          // b*L + l
    const int l = row & (L - 1);
    const int d0 = threadIdx.x * 4;
    float a[4];
    float wv[4][4];
    #pragma unroll
    for (int dd = 0; dd < 4; ++dd) {
        a[dd] = cb[d0 + dd];
        const float4 wr = *reinterpret_cast<const float4*>(cw + (size_t)(d0 + dd) * 4);
        wv[dd][0] = wr.x; wv[dd][1] = wr.y; wv[dd][2] = wr.z; wv[dd][3] = wr.w;
    }
    #pragma unroll
    for (int k = 0; k < 4; ++k) {
        if (l - 3 + k >= 0) {
            const ushort4 v = *reinterpret_cast<const ushort4*>(xn + (size_t)(row - 3 + k) * D + d0);
            a[0] += wv[0][k] * bf2f(v.x);
            a[1] += wv[1][k] * bf2f(v.y);
            a[2] += wv[2][k] * bf2f(v.z);
            a[3] += wv[3][k] * bf2f(v.w);
        }
    }
    ushort4 o;
    o.x = f2bf(a[0] * fsigmoid(a[0]));
    o.y = f2bf(a[1] * fsigmoid(a[1]));
    o.z = f2bf(a[2] * fsigmoid(a[2]));
    o.w = f2bf(a[3] * fsigmoid(a[3]));
    *reinterpret_cast<ushort4*>(xc + (size_t)row * D + d0) = o;
}

// ---------------- TM x 128 tile bf16 MFMA GEMM, m97-style simple loop -------
// 256 threads / 4 waves (2x2) / single LDS buffer / plain syncthreads + proven
// 0-conflict XOR swizzle. BKT=64 for the heavy GEMMs (halves barrier count per
// MFMA; LDS 32KB, grid-limited occupancy unaffected). BKT=32 for out-GEMM.
// MODE 0: out-GEMM. rows identity, W=owh, y = v + ob + x.
// MODE 3: MEGA. bid<1024: gate. bid>=1024: chunk rows x {delta|B|C}.
// MODE 4: TAIL. rows [512,4096)/batch x {delta|B|C}; exit unless need_tail.
template <int TM, int MODE, int BKT>
__global__ __launch_bounds__(256) void gemm_kernel(
    const unsigned short* __restrict__ A,
    const unsigned short* __restrict__ W,   // MODE 0: owh; MODE 3/4: W4
    const float* __restrict__ bias,         // MODE 0: ob; MODE 3: gb
    const float* __restrict__ pb,
    const float* __restrict__ xres,
    float* __restrict__ outf,
    unsigned short* __restrict__ outh,      // gate
    unsigned short* __restrict__ prm,
    const int* __restrict__ need_tail) {
    constexpr int K  = 1024;
    constexpr int WM = TM / 2;     // 64 or 32
    constexpr int MF = WM / 16;    // 4 or 2
    __shared__ alignas(16) unsigned short As[TM * BKT];
    __shared__ alignas(16) unsigned short Bs[128 * BKT];
    const int tid = threadIdx.x;
    const int wave = tid >> 6;
    const int lane = tid & 63;

    const int nwg = (int)gridDim.x;   // all grids % 8 == 0
    const int bid = ((int)blockIdx.x & 7) * (nwg >> 3) + ((int)blockIdx.x >> 3);

    int row0, wrow0;
    if constexpr (MODE == 0) {
        row0 = (bid >> 3) * TM;
        wrow0 = (bid & 7) << 7;
    } else if constexpr (MODE == 3) {
        if (bid < 1024) {                       // gate region
            row0 = (bid >> 3) * 128;
            wrow0 = (bid & 7) << 7;
        } else {                                // chunk region
            const int q = bid - 1024;
            const int rt = q / 24, ct = q % 24; // rt 0..15
            row0 = (rt >> 2) * L + (rt & 3) * 128;
            wrow0 = (ct < 8) ? (3072 + ct * 128)
                  : (ct < 16) ? (1024 + (ct - 8) * 128)
                  : (2048 + (ct - 16) * 128);
        }
    } else {                                    // MODE 4 tail
        const int rt = bid / 24, ct = bid % 24; // rt 0..111
        const int batch = rt / 28;
        if (!need_tail[batch]) return;          // block-uniform exit
        row0 = batch * L + CHUNK + (rt % 28) * 128;
        wrow0 = (ct < 8) ? (3072 + ct * 128)
              : (ct < 16) ? (1024 + (ct - 8) * 128)
              : (2048 + (ct - 16) * 128);
    }

    const int wr = wave >> 1, wc = wave & 1;
    const int lr = lane & 15, kg = lane >> 4;

    f32x4 acc[MF][4];
    #pragma unroll
    for (int i = 0; i < MF; ++i)
        #pragma unroll
        for (int j = 0; j < 4; ++j) acc[i][j] = (f32x4){0.f, 0.f, 0.f, 0.f};

    if constexpr (BKT == 32) {
        // stage: 4 threads/row; source col pre-swizzled with key (row>>1)&3
        const int s_row = tid >> 2;
        const int s_col = 8 * ((tid & 3) ^ ((tid >> 3) & 3));
        const unsigned short* aP = A + (size_t)(row0 + s_row) * K + s_col;
        const unsigned short* bP = W + (size_t)(wrow0 + s_row) * K + s_col;
        const int acol = (kg * 8) ^ (((lr >> 1) & 3) * 8);
        const int abase = (wr * WM + lr) * 32 + acol;
        const int bbase = (wc * 64 + lr) * 32 + acol;
        constexpr int AI = TM / 64;
        for (int k0 = 0; k0 < K; k0 += 32) {
            #pragma unroll
            for (int i = 0; i < AI; ++i)
                async_lds16(&As[(i * 256 + tid) * 8], aP + (size_t)(i * 64) * K + k0);
            #pragma unroll
            for (int i = 0; i < 2; ++i)
                async_lds16(&Bs[(i * 256 + tid) * 8], bP + (size_t)(i * 64) * K + k0);
            __syncthreads();
            short8 af[MF], bfv[4];
            #pragma unroll
            for (int mi = 0; mi < MF; ++mi)
                af[mi] = *reinterpret_cast<const short8*>(&As[abase + mi * 16 * 32]);
            #pragma unroll
            for (int ni = 0; ni < 4; ++ni)
                bfv[ni] = *reinterpret_cast<const short8*>(&Bs[bbase + ni * 16 * 32]);
            #pragma unroll
            for (int mi = 0; mi < MF; ++mi)
                #pragma unroll
                for (int ni = 0; ni < 4; ++ni)
                    acc[mi][ni] = __builtin_amdgcn_mfma_f32_16x16x32_bf16(af[mi], bfv[ni], acc[mi][ni], 0, 0, 0);
            __syncthreads();
        }
    } else {
        // BKT == 64: 8 threads/row; source granule pre-swizzled with key row&7
        const int s_row = tid >> 3;                            // 0..31
        const int s_col = 8 * ((tid & 7) ^ ((tid >> 3) & 7));  // inverse swizzle
        const unsigned short* aP = A + (size_t)(row0 + s_row) * K + s_col;
        const unsigned short* bP = W + (size_t)(wrow0 + s_row) * K + s_col;
        constexpr int AI = TM / 32;                            // 4 for TM=128
        const int arow = (wr * WM + lr) * 64;
        const int brow = (wc * 64 + lr) * 64;
        const int skey = (lr & 7) * 8;
        for (int k0 = 0; k0 < K; k0 += 64) {
            #pragma unroll
            for (int i = 0; i < AI; ++i)
                async_lds16(&As[(i * 256 + tid) * 8], aP + (size_t)(i * 32) * K + k0);
            #pragma unroll
            for (int i = 0; i < 4; ++i)
                async_lds16(&Bs[(i * 256 + tid) * 8], bP + (size_t)(i * 32) * K + k0);
            __syncthreads();
            #pragma unroll
            for (int ks = 0; ks < 2; ++ks) {
                const int sw = (ks * 32 + kg * 8) ^ skey;
                short8 af[MF], bfv[4];
                #pragma unroll
                for (int mi = 0; mi < MF; ++mi)
                    af[mi] = *reinterpret_cast<const short8*>(&As[arow + mi * 16 * 64 + sw]);
                #pragma unroll
                for (int ni = 0; ni < 4; ++ni)
                    bfv[ni] = *reinterpret_cast<const short8*>(&Bs[brow + ni * 16 * 64 + sw]);
                #pragma unroll
                for (int mi = 0; mi < MF; ++mi)
                    #pragma unroll
                    for (int ni = 0; ni < 4; ++ni)
                        acc[mi][ni] = __builtin_amdgcn_mfma_f32_16x16x32_bf16(af[mi], bfv[ni], acc[mi][ni], 0, 0, 0);
            }
            __syncthreads();
        }
    }

    const int r0 = row0 + wr * WM + kg * 4;
    if constexpr (MODE == 0) {
        const int c0 = wrow0 + wc * 64;
        #pragma unroll
        for (int mi = 0; mi < MF; ++mi)
            #pragma unroll
            for (int ni = 0; ni < 4; ++ni) {
                const int col = c0 + ni * 16 + lr;
                #pragma unroll
                for (int j = 0; j < 4; ++j) {
                    const int row = r0 + mi * 16 + j;
                    outf[(size_t)row * 1024 + col] =
                        acc[mi][ni][j] + bias[col] + xres[(size_t)row * 1024 + col];
                }
            }
    } else {
        const int region = wrow0 >> 10;       // 0 gate, 1 B, 2 C, 3 delta
        const int cwb = (wrow0 & 1023) + wc * 64;
        #pragma unroll
        for (int mi = 0; mi < MF; ++mi)
            #pragma unroll
            for (int ni = 0; ni < 4; ++ni) {
                const int cw = cwb + ni * 16 + lr;
                #pragma unroll
                for (int j = 0; j < 4; ++j) {
                    const int row = r0 + mi * 16 + j;
                    const float v = acc[mi][ni][j];
                    if (region == 0) {
                        outh[(size_t)row * 1024 + cw] = f2bf(fsigmoid(v + bias[cw]));
                    } else if (region == 3) {
                        const int idx = (cw >> 6) * 192 + (cw & 63);
                        prm[(size_t)row * NP + idx] = f2bf(fsigmoid(v + pb[idx]));
                    } else if (region == 1) {
                        const int idx = (cw >> 6) * 192 + 64 + (cw & 63);
                        prm[(size_t)row * NP + idx] = f2bf(v + pb[idx]);
                    } else {
                        const int idx = (cw >> 6) * 192 + 128 + (cw & 63);
                        prm[(size_t)row * NP + idx] = f2bf(v + pb[idx]);
                    }
                }
            }
    }
}

// ---------------- prefixA: per-head saturation within CHUNK -----------------
__global__ __launch_bounds__(64) void prefixA_kernel(const unsigned short* __restrict__ prm,
                                                     int* __restrict__ prefix2,
                                                     int* __restrict__ need_tail) {
    const int bh = blockIdx.x;           // b*16 + h
    const int b = bh >> 4, h = bh & 15;
    const int s = threadIdx.x;
    const unsigned short* base = prm + (size_t)b * L * NP + h * 192 + s;
    float p = 1.0f;
    int lsat = -1;
    for (int l = 0; l < CHUNK; l += 8) {
        float dv[8];
        #pragma unroll
        for (int j = 0; j < 8; ++j) dv[j] = bf2f(base[(size_t)(l + j) * NP]);
        #pragma unroll
        for (int j = 0; j < 8; ++j) p = p * dv[j];
        if (__all(p == 0.0f)) { lsat = l + 8; break; }
    }
    if (s == 0) {
        if (lsat >= 0) prefix2[bh] = lsat;
        else atomicOr(need_tail + b, 1);
    }
}

// ---------------- prefixB: full per-head rescan for unsaturated batches -----
__global__ __launch_bounds__(64) void prefixB_kernel(const unsigned short* __restrict__ prm,
                                                     int* __restrict__ prefix2,
                                                     const int* __restrict__ need_tail) {
    const int bh = blockIdx.x;
    const int b = bh >> 4, h = bh & 15;
    if (!need_tail[b]) return;
    const int s = threadIdx.x;
    const unsigned short* base = prm + (size_t)b * L * NP + h * 192 + s;
    float p = 1.0f;
    int lsat = L;
    for (int l = 0; l < L; l += 8) {
        float dv[8];
        #pragma unroll
        for (int j = 0; j < 8; ++j) dv[j] = bf2f(base[(size_t)(l + j) * NP]);
        #pragma unroll
        for (int j = 0; j < 8; ++j) p = p * dv[j];
        if (__all(p == 0.0f)) { lsat = l + 8; break; }
    }
    if (s == 0) prefix2[bh] = lsat;
}

// ---------------- selective scan (bf16 params in, bf16 ssm out) -------------
// Writes ssm rows [0, lsat) only; mix bounds its reads with prefix2[bh].
__global__ __launch_bounds__(64) void scan_kernel(const unsigned short* __restrict__ prm,
                                                  const float* __restrict__ state,
                                                  unsigned short* __restrict__ ssm,
                                                  float* __restrict__ hlast) {
    const int bh = blockIdx.x;           // b*16 + h
    const int b = bh >> 4, h = bh & 15;
    const int s = threadIdx.x;           // 0..63
    const unsigned short* base = prm + (size_t)b * L * NP + h * 192 + s;
    unsigned short* ob = ssm + (size_t)b * L * D + h * 64 + s;
    const float h0 = state[(size_t)bh * 64 + s];
    float p = 1.0f, cu = 0.0f;
    bool live = true;
    for (int l = 0; l < L && live; l += 8) {
        float dv[8], bv[8], cv[8];
        #pragma unroll
        for (int j = 0; j < 8; ++j) {
            const unsigned short* pp = base + (size_t)(l + j) * NP;
            dv[j] = bf2f(pp[0]);
            bv[j] = bf2f(pp[64]);
            cv[j] = bf2f(pp[128]);
        }
        #pragma unroll
        for (int j = 0; j < 8; ++j) {
            p = p * dv[j];
            const float u = bv[j] / (p + 1e-8f);
            cu += u;
            const float hh = p * (h0 + cu);
            ob[(size_t)(l + j) * D] = f2bf(cv[j] * hh);
        }
        if (__all(p == 0.0f)) live = false;
    }
    hlast[(size_t)bh * 64 + s] = live ? p * (h0 + cu) : 0.0f;
}

// ---------------- mix: mixed = g*ssm + (1-g)*xn -> bf16 (in place over gate) --
// One row per block; per-head ssm bound from prefix2.
__global__ __launch_bounds__(256) void mix_kernel(unsigned short* __restrict__ gate,
                                                  const unsigned short* __restrict__ ssm,
                                                  const unsigned short* __restrict__ xn,
                                                  const int* __restrict__ prefix2) {
    const size_t i = ((size_t)blockIdx.x * 256 + threadIdx.x) * 4;
    const int row = (int)(i >> 10);
    const int b = row >> 12;
    const int l = row & (L - 1);
    const int h = (int)((i >> 6) & 15);
    const ushort4 g4 = *reinterpret_cast<const ushort4*>(gate + i);
    const ushort4 x4 = *reinterpret_cast<const ushort4*>(xn + i);
    float sx = 0.f, sy = 0.f, sz = 0.f, sw = 0.f;
    if (l < prefix2[b * 16 + h]) {
        const ushort4 s4 = *reinterpret_cast<const ushort4*>(ssm + i);
        sx = bf2f(s4.x); sy = bf2f(s4.y); sz = bf2f(s4.z); sw = bf2f(s4.w);
    }
    ushort4 o;
    float g;
    g = bf2f(g4.x); o.x = f2bf(g * sx + (1.0f - g) * bf2f(x4.x));
    g = bf2f(g4.y); o.y = f2bf(g * sy + (1.0f - g) * bf2f(x4.y));
    g = bf2f(g4.z); o.z = f2bf(g * sz + (1.0f - g) * bf2f(x4.z));
    g = bf2f(g4.w); o.w = f2bf(g * sw + (1.0f - g) * bf2f(x4.w));
    *reinterpret_cast<ushort4*>(gate + i) = o;
}

extern "C" void kernel_launch(void* const* d_in, const int* in_sizes, int n_in,
                              void* d_out, int out_size, void* d_ws, size_t ws_size,
                              hipStream_t stream) {
    const float* x      = (const float*)d_in[0];
    const float* state  = (const float*)d_in[1];
    const float* norm_w = (const float*)d_in[2];
    const float* conv_w = (const float*)d_in[3];
    const float* conv_b = (const float*)d_in[4];
    const float* pw     = (const float*)d_in[5];
    const float* pb     = (const float*)d_in[6];
    const float* gw     = (const float*)d_in[7];
    const float* gb     = (const float*)d_in[8];
    const float* ow     = (const float*)d_in[9];
    const float* ob     = (const float*)d_in[10];

    // ws: gate 32MB | prm 96MB | W4 8MB | owh 2MB | flags (r2 proved >=138MB ok)
    constexpr size_t NEED = (138ull << 20) + 4096;
    if (ws_size < NEED) return;  // fail loudly instead of faulting

    char* ws = (char*)d_ws;
    unsigned short* gate  = (unsigned short*)(ws);                  // 32 MB (becomes mixed)
    unsigned short* mixed = gate;
    unsigned short* prm   = (unsigned short*)(ws + (32ull  << 20)); // 96 MB
    unsigned short* w4    = (unsigned short*)(ws + (128ull << 20)); // 8 MB
    unsigned short* owh   = (unsigned short*)(ws + (136ull << 20)); // 2 MB
    int*            need_tail = (int*)(ws + (138ull << 20));        // 16 B
    int*            prefix2   = need_tail + NB;                     // 256 B

    // d_out doubles as scratch until the final GEMM overwrites it with y.
    float* y = (float*)d_out;
    float* hlast = y + (size_t)M * D;
    unsigned short* xn  = (unsigned short*)d_out;                   // [0, 32MB)
    unsigned short* xc  = (unsigned short*)((char*)d_out + (32ull << 20)); // [32, 64MB)
    unsigned short* ssm = xc;  // scan overwrites xc region after mega/tail GEMMs

    prep_kernel<<<5120, 256, 0, stream>>>(gw, pw, ow, w4, owh, need_tail);

    rmsnorm_kernel<<<M, 256, 0, stream>>>(x, norm_w, xn);
    conv_silu_kernel<<<M, 256, 0, stream>>>(xn, conv_w, conv_b, xc);

    // MEGA (BK=64): gate (1024) + chunk delta/B/C (384) = 1408 blocks, all live
    gemm_kernel<128, 3, 64><<<1408, 256, 0, stream>>>(
        xc, w4, gb, pb, nullptr, nullptr, gate, prm, nullptr);

    prefixA_kernel<<<NB * H, 64, 0, stream>>>(prm, prefix2, need_tail);

    // TAIL (BK=64): rows [512,4096)/batch x delta/B/C; normally all blocks exit
    gemm_kernel<128, 4, 64><<<2688, 256, 0, stream>>>(
        xc, w4, nullptr, pb, nullptr, nullptr, nullptr, prm, need_tail);
    prefixB_kernel<<<NB * H, 64, 0, stream>>>(prm, prefix2, need_tail);

    scan_kernel<<<NB * H, 64, 0, stream>>>(prm, state, ssm, hlast);

    mix_kernel<<<(M * D) / 1024, 256, 0, stream>>>(gate, ssm, xn, prefix2);

    // out-GEMM (BK=32, TM=64): 2048 blocks (proven best in r12)
    gemm_kernel<64, 0, 32><<<2048, 256, 0, stream>>>(
        mixed, owh, ob, nullptr, x, y, nullptr, nullptr, nullptr);
}

// Round 16
// 232.849 us; speedup vs baseline: 1.2059x; 1.2059x over previous
//
#include <hip/hip_runtime.h>
#include <stdint.h>

typedef __attribute__((ext_vector_type(8))) short short8;
typedef __attribute__((ext_vector_type(4))) float f32x4;

static constexpr int D  = 1024;
static constexpr int H  = 16;
static constexpr int L  = 4096;
static constexpr int NB = 4;
static constexpr int M  = NB * L;      // 16384 rows
static constexpr int NP = 3 * H * 64;  // 3072 param cols
static constexpr int CHUNK = 512;      // B/C/delta guaranteed-compute prefix rows

__device__ __forceinline__ float bf2f(unsigned short u) {
    unsigned int v = ((unsigned int)u) << 16;
    return __builtin_bit_cast(float, v);
}
__device__ __forceinline__ unsigned short f2bf(float f) {
    unsigned int x = __builtin_bit_cast(unsigned int, f);
    x += 0x7fffu + ((x >> 16) & 1u);
    return (unsigned short)(x >> 16);
}
__device__ __forceinline__ float fsigmoid(float v) {
    return __builtin_amdgcn_rcpf(1.0f + __expf(-v));
}
__device__ __forceinline__ void async_lds16(void* lds, const void* g) {
    __builtin_amdgcn_global_load_lds(
        (const __attribute__((address_space(1))) unsigned int*)g,
        (__attribute__((address_space(3))) unsigned int*)lds,
        16, 0, 0);
}

// ---------------- prep: init flags + W4 cast + ow cast ---------------------
// W4 rows: [0,1024) gate gw | [1024,2048) B | [2048,3072) C | [3072,4096) delta
// blocks 4096..5119: owh rows.
__global__ __launch_bounds__(256) void prep_kernel(const float* __restrict__ gw,
                                                   const float* __restrict__ pw,
                                                   const float* __restrict__ ow,
                                                   unsigned short* __restrict__ w4,
                                                   unsigned short* __restrict__ owh,
                                                   int* __restrict__ need_tail) {
    if (blockIdx.x == 0 && threadIdx.x < NB) need_tail[threadIdx.x] = 0;
    const int rr = blockIdx.x;
    const float* src;
    unsigned short* dst;
    if (rr < 1024) {
        src = gw + (size_t)rr * 1024;
        dst = w4 + (size_t)rr * 1024;
    } else if (rr < 2048) {
        const int r = rr - 1024;
        src = pw + (size_t)((r >> 6) * 192 + 64 + (r & 63)) * 1024;
        dst = w4 + (size_t)rr * 1024;
    } else if (rr < 3072) {
        const int r = rr - 2048;
        src = pw + (size_t)((r >> 6) * 192 + 128 + (r & 63)) * 1024;
        dst = w4 + (size_t)rr * 1024;
    } else if (rr < 4096) {
        const int r = rr - 3072;
        src = pw + (size_t)((r >> 6) * 192 + (r & 63)) * 1024;
        dst = w4 + (size_t)rr * 1024;
    } else {
        const int r = rr - 4096;
        src = ow + (size_t)r * 1024;
        dst = owh + (size_t)r * 1024;
    }
    const int t = threadIdx.x * 4;
    const float4 v = *reinterpret_cast<const float4*>(src + t);
    ushort4 o;
    o.x = f2bf(v.x); o.y = f2bf(v.y); o.z = f2bf(v.z); o.w = f2bf(v.w);
    *reinterpret_cast<ushort4*>(dst + t) = o;
}

// ---------------- fused RMSNorm + causal conv(K=4) + SiLU ------------------
// Block owns 32 consecutive rows (batch-aligned: 4096 % 32 == 0); serial over
// rows with a block-wide reduction per row; conv consumes a 3-row register
// window of xn -> no xn re-read. Reduction/rounding code identical to r14
// (bit-identical xn/xc).
__global__ __launch_bounds__(256) void rmsconv_kernel(const float* __restrict__ x,
                                                      const float* __restrict__ nw,
                                                      const float* __restrict__ cw,
                                                      const float* __restrict__ cb,
                                                      unsigned short* __restrict__ xn,
                                                      unsigned short* __restrict__ xc) {
    constexpr int ROWS = 32;
    const int row0 = blockIdx.x * ROWS;
    const int t = threadIdx.x;
    const int d0 = t * 4;
    __shared__ float red[4];

    float wv[4][4], cb4[4];
    #pragma unroll
    for (int dd = 0; dd < 4; ++dd) {
        cb4[dd] = cb[d0 + dd];
        const float4 wr = *reinterpret_cast<const float4*>(cw + (size_t)(d0 + dd) * 4);
        wv[dd][0] = wr.x; wv[dd][1] = wr.y; wv[dd][2] = wr.z; wv[dd][3] = wr.w;
    }
    const float4 nw4 = *reinterpret_cast<const float4*>(nw + d0);

    auto rms_row = [&](int r) -> ushort4 {
        const float4 v = *reinterpret_cast<const float4*>(x + (size_t)r * D + d0);
        float s = v.x * v.x + v.y * v.y + v.z * v.z + v.w * v.w;
        #pragma unroll
        for (int o = 32; o > 0; o >>= 1) s += __shfl_down(s, o, 64);
        if ((t & 63) == 0) red[t >> 6] = s;
        __syncthreads();
        const float tot = red[0] + red[1] + red[2] + red[3];
        const float rinv = 1.0f / sqrtf(tot * (1.0f / D) + 1e-6f);
        __syncthreads();            // red safe to overwrite next row
        ushort4 o4;
        o4.x = f2bf(nw4.x * v.x * rinv);
        o4.y = f2bf(nw4.y * v.y * rinv);
        o4.z = f2bf(nw4.z * v.z * rinv);
        o4.w = f2bf(nw4.w * v.w * rinv);
        return o4;
    };

    const int l0 = row0 & (L - 1);
    ushort4 win[3] = {{0,0,0,0},{0,0,0,0},{0,0,0,0}};  // xn rows r-3,r-2,r-1
    if (l0 != 0) {                   // block-uniform
        #pragma unroll
        for (int w = 0; w < 3; ++w) win[w] = rms_row(row0 - 3 + w);
    }

    for (int rr = 0; rr < ROWS; ++rr) {
        const int r = row0 + rr;
        const int l = l0 + rr;
        const ushort4 xn4 = rms_row(r);
        *reinterpret_cast<ushort4*>(xn + (size_t)r * D + d0) = xn4;

        float a[4] = {cb4[0], cb4[1], cb4[2], cb4[3]};
        #pragma unroll
        for (int k = 0; k < 3; ++k) {
            if (l - 3 + k >= 0) {
                a[0] += wv[0][k] * bf2f(win[k].x);
                a[1] += wv[1][k] * bf2f(win[k].y);
                a[2] += wv[2][k] * bf2f(win[k].z);
                a[3] += wv[3][k] * bf2f(win[k].w);
            }
        }
        a[0] += wv[0][3] * bf2f(xn4.x);
        a[1] += wv[1][3] * bf2f(xn4.y);
        a[2] += wv[2][3] * bf2f(xn4.z);
        a[3] += wv[3][3] * bf2f(xn4.w);

        ushort4 o;
        o.x = f2bf(a[0] * fsigmoid(a[0]));
        o.y = f2bf(a[1] * fsigmoid(a[1]));
        o.z = f2bf(a[2] * fsigmoid(a[2]));
        o.w = f2bf(a[3] * fsigmoid(a[3]));
        *reinterpret_cast<ushort4*>(xc + (size_t)r * D + d0) = o;

        win[0] = win[1]; win[1] = win[2]; win[2] = xn4;
    }
}

// ---------------- TM x 128 tile bf16 MFMA GEMM, m97-style simple loop -------
// 256 threads / 4 waves (2x2) / BK=32 / single LDS buffer / plain syncthreads
// + proven 0-conflict XOR swizzle. (r15 measured BK=64 = regression: occupancy
// 26->19%, FETCH +12MB; BK=32 is the proven config.)
// MODE 0: out-GEMM. rows identity, W=owh, y = v + ob + x.
// MODE 3: MEGA. bid<1024: gate. bid>=1024: chunk rows x {delta|B|C}.
// MODE 4: TAIL. rows [512,4096)/batch x {delta|B|C}; exit unless need_tail.
template <int TM, int MODE>
__global__ __launch_bounds__(256) void gemm_kernel(
    const unsigned short* __restrict__ A,
    const unsigned short* __restrict__ W,   // MODE 0: owh; MODE 3/4: W4
    const float* __restrict__ bias,         // MODE 0: ob; MODE 3: gb
    const float* __restrict__ pb,
    const float* __restrict__ xres,
    float* __restrict__ outf,
    unsigned short* __restrict__ outh,      // gate
    unsigned short* __restrict__ prm,
    const int* __restrict__ need_tail) {
    constexpr int K  = 1024;
    constexpr int BK = 32;
    constexpr int WM = TM / 2;     // 64 or 32
    constexpr int MF = WM / 16;    // 4 or 2
    constexpr int AI = TM / 64;    // 2 or 1
    __shared__ alignas(16) unsigned short As[TM * BK];
    __shared__ alignas(16) unsigned short Bs[128 * BK];
    const int tid = threadIdx.x;
    const int wave = tid >> 6;
    const int lane = tid & 63;

    const int nwg = (int)gridDim.x;   // all grids % 8 == 0
    const int bid = ((int)blockIdx.x & 7) * (nwg >> 3) + ((int)blockIdx.x >> 3);

    int row0, wrow0;
    if constexpr (MODE == 0) {
        row0 = (bid >> 3) * TM;
        wrow0 = (bid & 7) << 7;
    } else if constexpr (MODE == 3) {
        if (bid < 1024) {                       // gate region
            row0 = (bid >> 3) * 128;
            wrow0 = (bid & 7) << 7;
        } else {                                // chunk region
            const int q = bid - 1024;
            const int rt = q / 24, ct = q % 24; // rt 0..15
            row0 = (rt >> 2) * L + (rt & 3) * 128;
            wrow0 = (ct < 8) ? (3072 + ct * 128)
                  : (ct < 16) ? (1024 + (ct - 8) * 128)
                  : (2048 + (ct - 16) * 128);
        }
    } else {                                    // MODE 4 tail
        const int rt = bid / 24, ct = bid % 24; // rt 0..111
        const int batch = rt / 28;
        if (!need_tail[batch]) return;          // block-uniform exit
        row0 = batch * L + CHUNK + (rt % 28) * 128;
        wrow0 = (ct < 8) ? (3072 + ct * 128)
              : (ct < 16) ? (1024 + (ct - 8) * 128)
              : (2048 + (ct - 16) * 128);
    }

    const int wr = wave >> 1, wc = wave & 1;
    const int lr = lane & 15, kg = lane >> 4;

    f32x4 acc[MF][4];
    #pragma unroll
    for (int i = 0; i < MF; ++i)
        #pragma unroll
        for (int j = 0; j < 4; ++j) acc[i][j] = (f32x4){0.f, 0.f, 0.f, 0.f};

    // staging: linear LDS dest, pre-swizzled global source column (G21)
    const int s_row = tid >> 2;                            // 0..63
    const int s_col = 8 * ((tid & 3) ^ ((tid >> 3) & 3));  // inverse swizzle
    const unsigned short* aP = A + (size_t)(row0 + s_row) * K + s_col;
    const unsigned short* bP = W + (size_t)(wrow0 + s_row) * K + s_col;

    // read-side swizzle
    const int acol = (kg * 8) ^ (((lr >> 1) & 3) * 8);
    const int abase = (wr * WM + lr) * BK + acol;
    const int bbase = (wc * 64 + lr) * BK + acol;

    for (int k0 = 0; k0 < K; k0 += BK) {
        #pragma unroll
        for (int i = 0; i < AI; ++i)
            async_lds16(&As[(i * 256 + tid) * 8], aP + (size_t)(i * 64) * K + k0);
        #pragma unroll
        for (int i = 0; i < 2; ++i)
            async_lds16(&Bs[(i * 256 + tid) * 8], bP + (size_t)(i * 64) * K + k0);
        __syncthreads();
        short8 af[MF], bfv[4];
        #pragma unroll
        for (int mi = 0; mi < MF; ++mi)
            af[mi] = *reinterpret_cast<const short8*>(&As[abase + mi * 16 * BK]);
        #pragma unroll
        for (int ni = 0; ni < 4; ++ni)
            bfv[ni] = *reinterpret_cast<const short8*>(&Bs[bbase + ni * 16 * BK]);
        #pragma unroll
        for (int mi = 0; mi < MF; ++mi)
            #pragma unroll
            for (int ni = 0; ni < 4; ++ni)
                acc[mi][ni] = __builtin_amdgcn_mfma_f32_16x16x32_bf16(af[mi], bfv[ni], acc[mi][ni], 0, 0, 0);
        __syncthreads();
    }

    const int r0 = row0 + wr * WM + kg * 4;
    if constexpr (MODE == 0) {
        const int c0 = wrow0 + wc * 64;
        #pragma unroll
        for (int mi = 0; mi < MF; ++mi)
            #pragma unroll
            for (int ni = 0; ni < 4; ++ni) {
                const int col = c0 + ni * 16 + lr;
                #pragma unroll
                for (int j = 0; j < 4; ++j) {
                    const int row = r0 + mi * 16 + j;
                    outf[(size_t)row * 1024 + col] =
                        acc[mi][ni][j] + bias[col] + xres[(size_t)row * 1024 + col];
                }
            }
    } else {
        const int region = wrow0 >> 10;       // 0 gate, 1 B, 2 C, 3 delta
        const int cwb = (wrow0 & 1023) + wc * 64;
        #pragma unroll
        for (int mi = 0; mi < MF; ++mi)
            #pragma unroll
            for (int ni = 0; ni < 4; ++ni) {
                const int cw = cwb + ni * 16 + lr;
                #pragma unroll
                for (int j = 0; j < 4; ++j) {
                    const int row = r0 + mi * 16 + j;
                    const float v = acc[mi][ni][j];
                    if (region == 0) {
                        outh[(size_t)row * 1024 + cw] = f2bf(fsigmoid(v + bias[cw]));
                    } else if (region == 3) {
                        const int idx = (cw >> 6) * 192 + (cw & 63);
                        prm[(size_t)row * NP + idx] = f2bf(fsigmoid(v + pb[idx]));
                    } else if (region == 1) {
                        const int idx = (cw >> 6) * 192 + 64 + (cw & 63);
                        prm[(size_t)row * NP + idx] = f2bf(v + pb[idx]);
                    } else {
                        const int idx = (cw >> 6) * 192 + 128 + (cw & 63);
                        prm[(size_t)row * NP + idx] = f2bf(v + pb[idx]);
                    }
                }
            }
    }
}

// ---------------- prefixA: per-head saturation within CHUNK -----------------
__global__ __launch_bounds__(64) void prefixA_kernel(const unsigned short* __restrict__ prm,
                                                     int* __restrict__ prefix2,
                                                     int* __restrict__ need_tail) {
    const int bh = blockIdx.x;           // b*16 + h
    const int b = bh >> 4, h = bh & 15;
    const int s = threadIdx.x;
    const unsigned short* base = prm + (size_t)b * L * NP + h * 192 + s;
    float p = 1.0f;
    int lsat = -1;
    for (int l = 0; l < CHUNK; l += 8) {
        float dv[8];
        #pragma unroll
        for (int j = 0; j < 8; ++j) dv[j] = bf2f(base[(size_t)(l + j) * NP]);
        #pragma unroll
        for (int j = 0; j < 8; ++j) p = p * dv[j];
        if (__all(p == 0.0f)) { lsat = l + 8; break; }
    }
    if (s == 0) {
        if (lsat >= 0) prefix2[bh] = lsat;
        else atomicOr(need_tail + b, 1);
    }
}

// ---------------- prefixB: full per-head rescan for unsaturated batches -----
__global__ __launch_bounds__(64) void prefixB_kernel(const unsigned short* __restrict__ prm,
                                                     int* __restrict__ prefix2,
                                                     const int* __restrict__ need_tail) {
    const int bh = blockIdx.x;
    const int b = bh >> 4, h = bh & 15;
    if (!need_tail[b]) return;
    const int s = threadIdx.x;
    const unsigned short* base = prm + (size_t)b * L * NP + h * 192 + s;
    float p = 1.0f;
    int lsat = L;
    for (int l = 0; l < L; l += 8) {
        float dv[8];
        #pragma unroll
        for (int j = 0; j < 8; ++j) dv[j] = bf2f(base[(size_t)(l + j) * NP]);
        #pragma unroll
        for (int j = 0; j < 8; ++j) p = p * dv[j];
        if (__all(p == 0.0f)) { lsat = l + 8; break; }
    }
    if (s == 0) prefix2[bh] = lsat;
}

// ---------------- selective scan (bf16 params in, bf16 ssm out) -------------
// Writes ssm rows [0, lsat) only; mix bounds its reads with prefix2[bh].
__global__ __launch_bounds__(64) void scan_kernel(const unsigned short* __restrict__ prm,
                                                  const float* __restrict__ state,
                                                  unsigned short* __restrict__ ssm,
                                                  float* __restrict__ hlast) {
    const int bh = blockIdx.x;           // b*16 + h
    const int b = bh >> 4, h = bh & 15;
    const int s = threadIdx.x;           // 0..63
    const unsigned short* base = prm + (size_t)b * L * NP + h * 192 + s;
    unsigned short* ob = ssm + (size_t)b * L * D + h * 64 + s;
    const float h0 = state[(size_t)bh * 64 + s];
    float p = 1.0f, cu = 0.0f;
    bool live = true;
    for (int l = 0; l < L && live; l += 8) {
        float dv[8], bv[8], cv[8];
        #pragma unroll
        for (int j = 0; j < 8; ++j) {
            const unsigned short* pp = base + (size_t)(l + j) * NP;
            dv[j] = bf2f(pp[0]);
            bv[j] = bf2f(pp[64]);
            cv[j] = bf2f(pp[128]);
        }
        #pragma unroll
        for (int j = 0; j < 8; ++j) {
            p = p * dv[j];
            const float u = bv[j] / (p + 1e-8f);
            cu += u;
            const float hh = p * (h0 + cu);
            ob[(size_t)(l + j) * D] = f2bf(cv[j] * hh);
        }
        if (__all(p == 0.0f)) live = false;
    }
    hlast[(size_t)bh * 64 + s] = live ? p * (h0 + cu) : 0.0f;
}

// ---------------- mix: mixed = g*ssm + (1-g)*xn -> bf16 (in place over gate) --
__global__ __launch_bounds__(256) void mix_kernel(unsigned short* __restrict__ gate,
                                                  const unsigned short* __restrict__ ssm,
                                                  const unsigned short* __restrict__ xn,
                                                  const int* __restrict__ prefix2) {
    const size_t i = ((size_t)blockIdx.x * 256 + threadIdx.x) * 4;
    const int row = (int)(i >> 10);
    const int b = row >> 12;
    const int l = row & (L - 1);
    const int h = (int)((i >> 6) & 15);
    const ushort4 g4 = *reinterpret_cast<const ushort4*>(gate + i);
    const ushort4 x4 = *reinterpret_cast<const ushort4*>(xn + i);
    float sx = 0.f, sy = 0.f, sz = 0.f, sw = 0.f;
    if (l < prefix2[b * 16 + h]) {
        const ushort4 s4 = *reinterpret_cast<const ushort4*>(ssm + i);
        sx = bf2f(s4.x); sy = bf2f(s4.y); sz = bf2f(s4.z); sw = bf2f(s4.w);
    }
    ushort4 o;
    float g;
    g = bf2f(g4.x); o.x = f2bf(g * sx + (1.0f - g) * bf2f(x4.x));
    g = bf2f(g4.y); o.y = f2bf(g * sy + (1.0f - g) * bf2f(x4.y));
    g = bf2f(g4.z); o.z = f2bf(g * sz + (1.0f - g) * bf2f(x4.z));
    g = bf2f(g4.w); o.w = f2bf(g * sw + (1.0f - g) * bf2f(x4.w));
    *reinterpret_cast<ushort4*>(gate + i) = o;
}

extern "C" void kernel_launch(void* const* d_in, const int* in_sizes, int n_in,
                              void* d_out, int out_size, void* d_ws, size_t ws_size,
                              hipStream_t stream) {
    const float* x      = (const float*)d_in[0];
    const float* state  = (const float*)d_in[1];
    const float* norm_w = (const float*)d_in[2];
    const float* conv_w = (const float*)d_in[3];
    const float* conv_b = (const float*)d_in[4];
    const float* pw     = (const float*)d_in[5];
    const float* pb     = (const float*)d_in[6];
    const float* gw     = (const float*)d_in[7];
    const float* gb     = (const float*)d_in[8];
    const float* ow     = (const float*)d_in[9];
    const float* ob     = (const float*)d_in[10];

    // ws: gate 32MB | prm 96MB | W4 8MB | owh 2MB | flags
    constexpr size_t NEED = (138ull << 20) + 4096;
    if (ws_size < NEED) return;  // fail loudly instead of faulting

    char* ws = (char*)d_ws;
    unsigned short* gate  = (unsigned short*)(ws);                  // 32 MB (becomes mixed)
    unsigned short* mixed = gate;
    unsigned short* prm   = (unsigned short*)(ws + (32ull  << 20)); // 96 MB
    unsigned short* w4    = (unsigned short*)(ws + (128ull << 20)); // 8 MB
    unsigned short* owh   = (unsigned short*)(ws + (136ull << 20)); // 2 MB
    int*            need_tail = (int*)(ws + (138ull << 20));        // 16 B
    int*            prefix2   = need_tail + NB;                     // 256 B

    // d_out doubles as scratch until the final GEMM overwrites it with y.
    float* y = (float*)d_out;
    float* hlast = y + (size_t)M * D;
    unsigned short* xn  = (unsigned short*)d_out;                   // [0, 32MB)
    unsigned short* xc  = (unsigned short*)((char*)d_out + (32ull << 20)); // [32, 64MB)
    unsigned short* ssm = xc;  // scan overwrites xc region after mega/tail GEMMs

    prep_kernel<<<5120, 256, 0, stream>>>(gw, pw, ow, w4, owh, need_tail);

    // fused RMSNorm + conv + SiLU: 512 blocks x 32 rows
    rmsconv_kernel<<<M / 32, 256, 0, stream>>>(x, norm_w, conv_w, conv_b, xn, xc);

    // MEGA (BK=32): gate (1024) + chunk delta/B/C (384) = 1408 blocks, all live
    gemm_kernel<128, 3><<<1408, 256, 0, stream>>>(
        xc, w4, gb, pb, nullptr, nullptr, gate, prm, nullptr);

    prefixA_kernel<<<NB * H, 64, 0, stream>>>(prm, prefix2, need_tail);

    // TAIL (BK=32): rows [512,4096)/batch x delta/B/C; normally all blocks exit
    gemm_kernel<128, 4><<<2688, 256, 0, stream>>>(
        xc, w4, nullptr, pb, nullptr, nullptr, nullptr, prm, need_tail);
    prefixB_kernel<<<NB * H, 64, 0, stream>>>(prm, prefix2, need_tail);

    scan_kernel<<<NB * H, 64, 0, stream>>>(prm, state, ssm, hlast);

    mix_kernel<<<(M * D) / 1024, 256, 0, stream>>>(gate, ssm, xn, prefix2);

    // out-GEMM (BK=32, TM=64): 2048 blocks (proven best in r12)
    gemm_kernel<64, 0><<<2048, 256, 0, stream>>>(
        mixed, owh, ob, nullptr, x, y, nullptr, nullptr, nullptr);
}

// Round 17
// 224.337 us; speedup vs baseline: 1.2516x; 1.0379x over previous
//
#include <hip/hip_runtime.h>
#include <stdint.h>

typedef __attribute__((ext_vector_type(8))) short short8;
typedef __attribute__((ext_vector_type(4))) float f32x4;

static constexpr int D  = 1024;
static constexpr int H  = 16;
static constexpr int L  = 4096;
static constexpr int NB = 4;
static constexpr int M  = NB * L;      // 16384 rows
static constexpr int NP = 3 * H * 64;  // 3072 param cols
static constexpr int CHUNK = 256;      // B/C/delta guaranteed-compute prefix rows

__device__ __forceinline__ float bf2f(unsigned short u) {
    unsigned int v = ((unsigned int)u) << 16;
    return __builtin_bit_cast(float, v);
}
__device__ __forceinline__ unsigned short f2bf(float f) {
    unsigned int x = __builtin_bit_cast(unsigned int, f);
    x += 0x7fffu + ((x >> 16) & 1u);
    return (unsigned short)(x >> 16);
}
__device__ __forceinline__ float fsigmoid(float v) {
    return __builtin_amdgcn_rcpf(1.0f + __expf(-v));
}
__device__ __forceinline__ void async_lds16(void* lds, const void* g) {
    __builtin_amdgcn_global_load_lds(
        (const __attribute__((address_space(1))) unsigned int*)g,
        (__attribute__((address_space(3))) unsigned int*)lds,
        16, 0, 0);
}

// ---------------- prep: init flags + W4 cast + ow cast ---------------------
// W4 rows: [0,1024) gate gw | [1024,2048) B | [2048,3072) C | [3072,4096) delta
// blocks 4096..5119: owh rows.
__global__ __launch_bounds__(256) void prep_kernel(const float* __restrict__ gw,
                                                   const float* __restrict__ pw,
                                                   const float* __restrict__ ow,
                                                   unsigned short* __restrict__ w4,
                                                   unsigned short* __restrict__ owh,
                                                   int* __restrict__ need_tail) {
    if (blockIdx.x == 0 && threadIdx.x < NB) need_tail[threadIdx.x] = 0;
    const int rr = blockIdx.x;
    const float* src;
    unsigned short* dst;
    if (rr < 1024) {
        src = gw + (size_t)rr * 1024;
        dst = w4 + (size_t)rr * 1024;
    } else if (rr < 2048) {
        const int r = rr - 1024;
        src = pw + (size_t)((r >> 6) * 192 + 64 + (r & 63)) * 1024;
        dst = w4 + (size_t)rr * 1024;
    } else if (rr < 3072) {
        const int r = rr - 2048;
        src = pw + (size_t)((r >> 6) * 192 + 128 + (r & 63)) * 1024;
        dst = w4 + (size_t)rr * 1024;
    } else if (rr < 4096) {
        const int r = rr - 3072;
        src = pw + (size_t)((r >> 6) * 192 + (r & 63)) * 1024;
        dst = w4 + (size_t)rr * 1024;
    } else {
        const int r = rr - 4096;
        src = ow + (size_t)r * 1024;
        dst = owh + (size_t)r * 1024;
    }
    const int t = threadIdx.x * 4;
    const float4 v = *reinterpret_cast<const float4*>(src + t);
    ushort4 o;
    o.x = f2bf(v.x); o.y = f2bf(v.y); o.z = f2bf(v.z); o.w = f2bf(v.w);
    *reinterpret_cast<ushort4*>(dst + t) = o;
}

// ---------------- fused RMSNorm + causal conv(K=4) + SiLU ------------------
// Block owns 32 consecutive rows (batch-aligned); serial over rows with a
// block-wide reduction per row; conv consumes a 3-row register window of xn.
__global__ __launch_bounds__(256) void rmsconv_kernel(const float* __restrict__ x,
                                                      const float* __restrict__ nw,
                                                      const float* __restrict__ cw,
                                                      const float* __restrict__ cb,
                                                      unsigned short* __restrict__ xn,
                                                      unsigned short* __restrict__ xc) {
    constexpr int ROWS = 32;
    const int row0 = blockIdx.x * ROWS;
    const int t = threadIdx.x;
    const int d0 = t * 4;
    __shared__ float red[4];

    float wv[4][4], cb4[4];
    #pragma unroll
    for (int dd = 0; dd < 4; ++dd) {
        cb4[dd] = cb[d0 + dd];
        const float4 wr = *reinterpret_cast<const float4*>(cw + (size_t)(d0 + dd) * 4);
        wv[dd][0] = wr.x; wv[dd][1] = wr.y; wv[dd][2] = wr.z; wv[dd][3] = wr.w;
    }
    const float4 nw4 = *reinterpret_cast<const float4*>(nw + d0);

    auto rms_row = [&](int r) -> ushort4 {
        const float4 v = *reinterpret_cast<const float4*>(x + (size_t)r * D + d0);
        float s = v.x * v.x + v.y * v.y + v.z * v.z + v.w * v.w;
        #pragma unroll
        for (int o = 32; o > 0; o >>= 1) s += __shfl_down(s, o, 64);
        if ((t & 63) == 0) red[t >> 6] = s;
        __syncthreads();
        const float tot = red[0] + red[1] + red[2] + red[3];
        const float rinv = 1.0f / sqrtf(tot * (1.0f / D) + 1e-6f);
        __syncthreads();            // red safe to overwrite next row
        ushort4 o4;
        o4.x = f2bf(nw4.x * v.x * rinv);
        o4.y = f2bf(nw4.y * v.y * rinv);
        o4.z = f2bf(nw4.z * v.z * rinv);
        o4.w = f2bf(nw4.w * v.w * rinv);
        return o4;
    };

    const int l0 = row0 & (L - 1);
    ushort4 win[3] = {{0,0,0,0},{0,0,0,0},{0,0,0,0}};  // xn rows r-3,r-2,r-1
    if (l0 != 0) {                   // block-uniform
        #pragma unroll
        for (int w = 0; w < 3; ++w) win[w] = rms_row(row0 - 3 + w);
    }

    for (int rr = 0; rr < ROWS; ++rr) {
        const int r = row0 + rr;
        const int l = l0 + rr;
        const ushort4 xn4 = rms_row(r);
        *reinterpret_cast<ushort4*>(xn + (size_t)r * D + d0) = xn4;

        float a[4] = {cb4[0], cb4[1], cb4[2], cb4[3]};
        #pragma unroll
        for (int k = 0; k < 3; ++k) {
            if (l - 3 + k >= 0) {
                a[0] += wv[0][k] * bf2f(win[k].x);
                a[1] += wv[1][k] * bf2f(win[k].y);
                a[2] += wv[2][k] * bf2f(win[k].z);
                a[3] += wv[3][k] * bf2f(win[k].w);
            }
        }
        a[0] += wv[0][3] * bf2f(xn4.x);
        a[1] += wv[1][3] * bf2f(xn4.y);
        a[2] += wv[2][3] * bf2f(xn4.z);
        a[3] += wv[3][3] * bf2f(xn4.w);

        ushort4 o;
        o.x = f2bf(a[0] * fsigmoid(a[0]));
        o.y = f2bf(a[1] * fsigmoid(a[1]));
        o.z = f2bf(a[2] * fsigmoid(a[2]));
        o.w = f2bf(a[3] * fsigmoid(a[3]));
        *reinterpret_cast<ushort4*>(xc + (size_t)r * D + d0) = o;

        win[0] = win[1]; win[1] = win[2]; win[2] = xn4;
    }
}

// ---------------- TM x 128 tile bf16 MFMA GEMM, m97-style simple loop -------
// 256 threads / 4 waves (2x2) / BK=32 / single LDS buffer / plain syncthreads
// + proven 0-conflict XOR swizzle.
// MODE 0: out-GEMM. rows identity, W=owh, y = v + ob + x. (TM=128 this round)
// MODE 3: MEGA. bid<1024: gate. bid>=1024: chunk rows (256/batch) x {delta|B|C}.
// MODE 4: TAIL. rows [256,4096)/batch x {delta|B|C}; exit unless need_tail.
template <int TM, int MODE>
__global__ __launch_bounds__(256) void gemm_kernel(
    const unsigned short* __restrict__ A,
    const unsigned short* __restrict__ W,   // MODE 0: owh; MODE 3/4: W4
    const float* __restrict__ bias,         // MODE 0: ob; MODE 3: gb
    const float* __restrict__ pb,
    const float* __restrict__ xres,
    float* __restrict__ outf,
    unsigned short* __restrict__ outh,      // gate
    unsigned short* __restrict__ prm,
    const int* __restrict__ need_tail) {
    constexpr int K  = 1024;
    constexpr int BK = 32;
    constexpr int WM = TM / 2;     // 64 or 32
    constexpr int MF = WM / 16;    // 4 or 2
    constexpr int AI = TM / 64;    // 2 or 1
    __shared__ alignas(16) unsigned short As[TM * BK];
    __shared__ alignas(16) unsigned short Bs[128 * BK];
    const int tid = threadIdx.x;
    const int wave = tid >> 6;
    const int lane = tid & 63;

    const int nwg = (int)gridDim.x;   // all grids % 8 == 0
    const int bid = ((int)blockIdx.x & 7) * (nwg >> 3) + ((int)blockIdx.x >> 3);

    int row0, wrow0;
    if constexpr (MODE == 0) {
        row0 = (bid >> 3) * TM;
        wrow0 = (bid & 7) << 7;
    } else if constexpr (MODE == 3) {
        if (bid < 1024) {                       // gate region
            row0 = (bid >> 3) * 128;
            wrow0 = (bid & 7) << 7;
        } else {                                // chunk region (256 rows/batch)
            const int q = bid - 1024;
            const int rt = q / 24, ct = q % 24; // rt 0..7
            row0 = (rt >> 1) * L + (rt & 1) * 128;
            wrow0 = (ct < 8) ? (3072 + ct * 128)
                  : (ct < 16) ? (1024 + (ct - 8) * 128)
                  : (2048 + (ct - 16) * 128);
        }
    } else {                                    // MODE 4 tail
        const int rt = bid / 24, ct = bid % 24; // rt 0..119
        const int batch = rt / 30;
        if (!need_tail[batch]) return;          // block-uniform exit
        row0 = batch * L + CHUNK + (rt % 30) * 128;
        wrow0 = (ct < 8) ? (3072 + ct * 128)
              : (ct < 16) ? (1024 + (ct - 8) * 128)
              : (2048 + (ct - 16) * 128);
    }

    const int wr = wave >> 1, wc = wave & 1;
    const int lr = lane & 15, kg = lane >> 4;

    f32x4 acc[MF][4];
    #pragma unroll
    for (int i = 0; i < MF; ++i)
        #pragma unroll
        for (int j = 0; j < 4; ++j) acc[i][j] = (f32x4){0.f, 0.f, 0.f, 0.f};

    // staging: linear LDS dest, pre-swizzled global source column (G21)
    const int s_row = tid >> 2;                            // 0..63
    const int s_col = 8 * ((tid & 3) ^ ((tid >> 3) & 3));  // inverse swizzle
    const unsigned short* aP = A + (size_t)(row0 + s_row) * K + s_col;
    const unsigned short* bP = W + (size_t)(wrow0 + s_row) * K + s_col;

    // read-side swizzle
    const int acol = (kg * 8) ^ (((lr >> 1) & 3) * 8);
    const int abase = (wr * WM + lr) * BK + acol;
    const int bbase = (wc * 64 + lr) * BK + acol;

    for (int k0 = 0; k0 < K; k0 += BK) {
        #pragma unroll
        for (int i = 0; i < AI; ++i)
            async_lds16(&As[(i * 256 + tid) * 8], aP + (size_t)(i * 64) * K + k0);
        #pragma unroll
        for (int i = 0; i < 2; ++i)
            async_lds16(&Bs[(i * 256 + tid) * 8], bP + (size_t)(i * 64) * K + k0);
        __syncthreads();
        short8 af[MF], bfv[4];
        #pragma unroll
        for (int mi = 0; mi < MF; ++mi)
            af[mi] = *reinterpret_cast<const short8*>(&As[abase + mi * 16 * BK]);
        #pragma unroll
        for (int ni = 0; ni < 4; ++ni)
            bfv[ni] = *reinterpret_cast<const short8*>(&Bs[bbase + ni * 16 * BK]);
        #pragma unroll
        for (int mi = 0; mi < MF; ++mi)
            #pragma unroll
            for (int ni = 0; ni < 4; ++ni)
                acc[mi][ni] = __builtin_amdgcn_mfma_f32_16x16x32_bf16(af[mi], bfv[ni], acc[mi][ni], 0, 0, 0);
        __syncthreads();
    }

    const int r0 = row0 + wr * WM + kg * 4;
    if constexpr (MODE == 0) {
        const int c0 = wrow0 + wc * 64;
        #pragma unroll
        for (int mi = 0; mi < MF; ++mi)
            #pragma unroll
            for (int ni = 0; ni < 4; ++ni) {
                const int col = c0 + ni * 16 + lr;
                #pragma unroll
                for (int j = 0; j < 4; ++j) {
                    const int row = r0 + mi * 16 + j;
                    outf[(size_t)row * 1024 + col] =
                        acc[mi][ni][j] + bias[col] + xres[(size_t)row * 1024 + col];
                }
            }
    } else {
        const int region = wrow0 >> 10;       // 0 gate, 1 B, 2 C, 3 delta
        const int cwb = (wrow0 & 1023) + wc * 64;
        #pragma unroll
        for (int mi = 0; mi < MF; ++mi)
            #pragma unroll
            for (int ni = 0; ni < 4; ++ni) {
                const int cw = cwb + ni * 16 + lr;
                #pragma unroll
                for (int j = 0; j < 4; ++j) {
                    const int row = r0 + mi * 16 + j;
                    const float v = acc[mi][ni][j];
                    if (region == 0) {
                        outh[(size_t)row * 1024 + cw] = f2bf(fsigmoid(v + bias[cw]));
                    } else if (region == 3) {
                        const int idx = (cw >> 6) * 192 + (cw & 63);
                        prm[(size_t)row * NP + idx] = f2bf(fsigmoid(v + pb[idx]));
                    } else if (region == 1) {
                        const int idx = (cw >> 6) * 192 + 64 + (cw & 63);
                        prm[(size_t)row * NP + idx] = f2bf(v + pb[idx]);
                    } else {
                        const int idx = (cw >> 6) * 192 + 128 + (cw & 63);
                        prm[(size_t)row * NP + idx] = f2bf(v + pb[idx]);
                    }
                }
            }
    }
}

// ---------------- prefixA: per-head saturation within CHUNK -> need_tail ----
__global__ __launch_bounds__(64) void prefixA_kernel(const unsigned short* __restrict__ prm,
                                                     int* __restrict__ need_tail) {
    const int bh = blockIdx.x;           // b*16 + h
    const int b = bh >> 4, h = bh & 15;
    const int s = threadIdx.x;
    const unsigned short* base = prm + (size_t)b * L * NP + h * 192 + s;
    float p = 1.0f;
    bool sat = false;
    for (int l = 0; l < CHUNK; l += 8) {
        float dv[8];
        #pragma unroll
        for (int j = 0; j < 8; ++j) dv[j] = bf2f(base[(size_t)(l + j) * NP]);
        #pragma unroll
        for (int j = 0; j < 8; ++j) p = p * dv[j];
        if (__all(p == 0.0f)) { sat = true; break; }
    }
    if (s == 0 && !sat) atomicOr(need_tail + b, 1);
}

// ---------------- selective scan (bf16 params in, bf16 ssm out) -------------
// Writes ssm rows [0, lend) and prefix2[bh] = lend (mix's read bound).
__global__ __launch_bounds__(64) void scan_kernel(const unsigned short* __restrict__ prm,
                                                  const float* __restrict__ state,
                                                  unsigned short* __restrict__ ssm,
                                                  float* __restrict__ hlast,
                                                  int* __restrict__ prefix2) {
    const int bh = blockIdx.x;           // b*16 + h
    const int b = bh >> 4, h = bh & 15;
    const int s = threadIdx.x;           // 0..63
    const unsigned short* base = prm + (size_t)b * L * NP + h * 192 + s;
    unsigned short* ob = ssm + (size_t)b * L * D + h * 64 + s;
    const float h0 = state[(size_t)bh * 64 + s];
    float p = 1.0f, cu = 0.0f;
    bool live = true;
    int lend = 0;
    for (int l = 0; l < L && live; l += 8) {
        float dv[8], bv[8], cv[8];
        #pragma unroll
        for (int j = 0; j < 8; ++j) {
            const unsigned short* pp = base + (size_t)(l + j) * NP;
            dv[j] = bf2f(pp[0]);
            bv[j] = bf2f(pp[64]);
            cv[j] = bf2f(pp[128]);
        }
        #pragma unroll
        for (int j = 0; j < 8; ++j) {
            p = p * dv[j];
            const float u = bv[j] / (p + 1e-8f);
            cu += u;
            const float hh = p * (h0 + cu);
            ob[(size_t)(l + j) * D] = f2bf(cv[j] * hh);
        }
        lend = l + 8;
        if (__all(p == 0.0f)) live = false;
    }
    hlast[(size_t)bh * 64 + s] = live ? p * (h0 + cu) : 0.0f;
    if (s == 0) prefix2[bh] = live ? L : lend;
}

// ---------------- mix: mixed = g*ssm + (1-g)*xn -> bf16 (in place over gate) --
__global__ __launch_bounds__(256) void mix_kernel(unsigned short* __restrict__ gate,
                                                  const unsigned short* __restrict__ ssm,
                                                  const unsigned short* __restrict__ xn,
                                                  const int* __restrict__ prefix2) {
    const size_t i = ((size_t)blockIdx.x * 256 + threadIdx.x) * 4;
    const int row = (int)(i >> 10);
    const int b = row >> 12;
    const int l = row & (L - 1);
    const int h = (int)((i >> 6) & 15);
    const ushort4 g4 = *reinterpret_cast<const ushort4*>(gate + i);
    const ushort4 x4 = *reinterpret_cast<const ushort4*>(xn + i);
    float sx = 0.f, sy = 0.f, sz = 0.f, sw = 0.f;
    if (l < prefix2[b * 16 + h]) {
        const ushort4 s4 = *reinterpret_cast<const ushort4*>(ssm + i);
        sx = bf2f(s4.x); sy = bf2f(s4.y); sz = bf2f(s4.z); sw = bf2f(s4.w);
    }
    ushort4 o;
    float g;
    g = bf2f(g4.x); o.x = f2bf(g * sx + (1.0f - g) * bf2f(x4.x));
    g = bf2f(g4.y); o.y = f2bf(g * sy + (1.0f - g) * bf2f(x4.y));
    g = bf2f(g4.z); o.z = f2bf(g * sz + (1.0f - g) * bf2f(x4.z));
    g = bf2f(g4.w); o.w = f2bf(g * sw + (1.0f - g) * bf2f(x4.w));
    *reinterpret_cast<ushort4*>(gate + i) = o;
}

extern "C" void kernel_launch(void* const* d_in, const int* in_sizes, int n_in,
                              void* d_out, int out_size, void* d_ws, size_t ws_size,
                              hipStream_t stream) {
    const float* x      = (const float*)d_in[0];
    const float* state  = (const float*)d_in[1];
    const float* norm_w = (const float*)d_in[2];
    const float* conv_w = (const float*)d_in[3];
    const float* conv_b = (const float*)d_in[4];
    const float* pw     = (const float*)d_in[5];
    const float* pb     = (const float*)d_in[6];
    const float* gw     = (const float*)d_in[7];
    const float* gb     = (const float*)d_in[8];
    const float* ow     = (const float*)d_in[9];
    const float* ob     = (const float*)d_in[10];

    // ws: gate 32MB | prm 96MB | W4 8MB | owh 2MB | flags
    constexpr size_t NEED = (138ull << 20) + 4096;
    if (ws_size < NEED) return;  // fail loudly instead of faulting

    char* ws = (char*)d_ws;
    unsigned short* gate  = (unsigned short*)(ws);                  // 32 MB (becomes mixed)
    unsigned short* mixed = gate;
    unsigned short* prm   = (unsigned short*)(ws + (32ull  << 20)); // 96 MB
    unsigned short* w4    = (unsigned short*)(ws + (128ull << 20)); // 8 MB
    unsigned short* owh   = (unsigned short*)(ws + (136ull << 20)); // 2 MB
    int*            need_tail = (int*)(ws + (138ull << 20));        // 16 B
    int*            prefix2   = need_tail + NB;                     // 256 B

    // d_out doubles as scratch until the final GEMM overwrites it with y.
    float* y = (float*)d_out;
    float* hlast = y + (size_t)M * D;
    unsigned short* xn  = (unsigned short*)d_out;                   // [0, 32MB)
    unsigned short* xc  = (unsigned short*)((char*)d_out + (32ull << 20)); // [32, 64MB)
    unsigned short* ssm = xc;  // scan overwrites xc region after mega/tail GEMMs

    prep_kernel<<<5120, 256, 0, stream>>>(gw, pw, ow, w4, owh, need_tail);

    // fused RMSNorm + conv + SiLU: 512 blocks x 32 rows
    rmsconv_kernel<<<M / 32, 256, 0, stream>>>(x, norm_w, conv_w, conv_b, xn, xc);

    // MEGA (BK=32): gate (1024) + chunk delta/B/C (192) = 1216 blocks, all live
    gemm_kernel<128, 3><<<1216, 256, 0, stream>>>(
        xc, w4, gb, pb, nullptr, nullptr, gate, prm, nullptr);

    prefixA_kernel<<<NB * H, 64, 0, stream>>>(prm, need_tail);

    // TAIL (BK=32): rows [256,4096)/batch x delta/B/C; normally all blocks exit
    gemm_kernel<128, 4><<<2880, 256, 0, stream>>>(
        xc, w4, nullptr, pb, nullptr, nullptr, nullptr, prm, need_tail);

    scan_kernel<<<NB * H, 64, 0, stream>>>(prm, state, ssm, hlast, prefix2);

    mix_kernel<<<(M * D) / 1024, 256, 0, stream>>>(gate, ssm, xn, prefix2);

    // out-GEMM: TM=128 -> 128x8 = 1024 blocks (better MFMA:stage ratio; r13
    // showed TM=128 > TM=64 per-FLOP at same structure)
    gemm_kernel<128, 0><<<1024, 256, 0, stream>>>(
        mixed, owh, ob, nullptr, x, y, nullptr, nullptr, nullptr);
}

// Round 18
// 218.206 us; speedup vs baseline: 1.2868x; 1.0281x over previous
//
#include <hip/hip_runtime.h>
#include <stdint.h>

typedef __attribute__((ext_vector_type(8))) short short8;
typedef __attribute__((ext_vector_type(4))) float f32x4;

static constexpr int D  = 1024;
static constexpr int H  = 16;
static constexpr int L  = 4096;
static constexpr int NB = 4;
static constexpr int M  = NB * L;      // 16384 rows
static constexpr int NP = 3 * H * 64;  // 3072 param cols
static constexpr int CHUNK = 256;      // B/C/delta guaranteed-compute prefix rows

__device__ __forceinline__ float bf2f(unsigned short u) {
    unsigned int v = ((unsigned int)u) << 16;
    return __builtin_bit_cast(float, v);
}
__device__ __forceinline__ unsigned short f2bf(float f) {
    unsigned int x = __builtin_bit_cast(unsigned int, f);
    x += 0x7fffu + ((x >> 16) & 1u);
    return (unsigned short)(x >> 16);
}
__device__ __forceinline__ float fsigmoid(float v) {
    return __builtin_amdgcn_rcpf(1.0f + __expf(-v));
}
__device__ __forceinline__ void async_lds16(void* lds, const void* g) {
    __builtin_amdgcn_global_load_lds(
        (const __attribute__((address_space(1))) unsigned int*)g,
        (__attribute__((address_space(3))) unsigned int*)lds,
        16, 0, 0);
}

// ---------------- fused front kernel --------------------------------------
// blocks [0,512): RMSNorm+conv+SiLU over 32 rows each (register window).
// blocks [512,5632): weight casts. W4 rows: gate | B | C | delta; then owh.
__global__ __launch_bounds__(256) void front_kernel(const float* __restrict__ x,
                                                    const float* __restrict__ nw,
                                                    const float* __restrict__ cw,
                                                    const float* __restrict__ cb,
                                                    const float* __restrict__ gw,
                                                    const float* __restrict__ pw,
                                                    const float* __restrict__ ow,
                                                    unsigned short* __restrict__ xn,
                                                    unsigned short* __restrict__ xc,
                                                    unsigned short* __restrict__ w4,
                                                    unsigned short* __restrict__ owh,
                                                    int* __restrict__ need_tail) {
    const int t = threadIdx.x;
    if (blockIdx.x == 0 && t < NB) need_tail[t] = 0;

    if (blockIdx.x >= 512) {
        // ---- weight cast path ----
        const int rr = (int)blockIdx.x - 512;
        const float* src;
        unsigned short* dst;
        if (rr < 1024) {
            src = gw + (size_t)rr * 1024;
            dst = w4 + (size_t)rr * 1024;
        } else if (rr < 2048) {
            const int r = rr - 1024;
            src = pw + (size_t)((r >> 6) * 192 + 64 + (r & 63)) * 1024;
            dst = w4 + (size_t)rr * 1024;
        } else if (rr < 3072) {
            const int r = rr - 2048;
            src = pw + (size_t)((r >> 6) * 192 + 128 + (r & 63)) * 1024;
            dst = w4 + (size_t)rr * 1024;
        } else if (rr < 4096) {
            const int r = rr - 3072;
            src = pw + (size_t)((r >> 6) * 192 + (r & 63)) * 1024;
            dst = w4 + (size_t)rr * 1024;
        } else {
            const int r = rr - 4096;
            src = ow + (size_t)r * 1024;
            dst = owh + (size_t)r * 1024;
        }
        const int tt = t * 4;
        const float4 v = *reinterpret_cast<const float4*>(src + tt);
        ushort4 o;
        o.x = f2bf(v.x); o.y = f2bf(v.y); o.z = f2bf(v.z); o.w = f2bf(v.w);
        *reinterpret_cast<ushort4*>(dst + tt) = o;
        return;
    }

    // ---- RMSNorm + conv + SiLU path ----
    constexpr int ROWS = 32;
    const int row0 = (int)blockIdx.x * ROWS;
    const int d0 = t * 4;
    __shared__ float red[4];

    float wv[4][4], cb4[4];
    #pragma unroll
    for (int dd = 0; dd < 4; ++dd) {
        cb4[dd] = cb[d0 + dd];
        const float4 wr = *reinterpret_cast<const float4*>(cw + (size_t)(d0 + dd) * 4);
        wv[dd][0] = wr.x; wv[dd][1] = wr.y; wv[dd][2] = wr.z; wv[dd][3] = wr.w;
    }
    const float4 nw4 = *reinterpret_cast<const float4*>(nw + d0);

    auto rms_row = [&](int r) -> ushort4 {
        const float4 v = *reinterpret_cast<const float4*>(x + (size_t)r * D + d0);
        float s = v.x * v.x + v.y * v.y + v.z * v.z + v.w * v.w;
        #pragma unroll
        for (int o = 32; o > 0; o >>= 1) s += __shfl_down(s, o, 64);
        if ((t & 63) == 0) red[t >> 6] = s;
        __syncthreads();
        const float tot = red[0] + red[1] + red[2] + red[3];
        const float rinv = 1.0f / sqrtf(tot * (1.0f / D) + 1e-6f);
        __syncthreads();
        ushort4 o4;
        o4.x = f2bf(nw4.x * v.x * rinv);
        o4.y = f2bf(nw4.y * v.y * rinv);
        o4.z = f2bf(nw4.z * v.z * rinv);
        o4.w = f2bf(nw4.w * v.w * rinv);
        return o4;
    };

    const int l0 = row0 & (L - 1);
    ushort4 win[3] = {{0,0,0,0},{0,0,0,0},{0,0,0,0}};
    if (l0 != 0) {
        #pragma unroll
        for (int w = 0; w < 3; ++w) win[w] = rms_row(row0 - 3 + w);
    }

    for (int rr = 0; rr < ROWS; ++rr) {
        const int r = row0 + rr;
        const int l = l0 + rr;
        const ushort4 xn4 = rms_row(r);
        *reinterpret_cast<ushort4*>(xn + (size_t)r * D + d0) = xn4;

        float a[4] = {cb4[0], cb4[1], cb4[2], cb4[3]};
        #pragma unroll
        for (int k = 0; k < 3; ++k) {
            if (l - 3 + k >= 0) {
                a[0] += wv[0][k] * bf2f(win[k].x);
                a[1] += wv[1][k] * bf2f(win[k].y);
                a[2] += wv[2][k] * bf2f(win[k].z);
                a[3] += wv[3][k] * bf2f(win[k].w);
            }
        }
        a[0] += wv[0][3] * bf2f(xn4.x);
        a[1] += wv[1][3] * bf2f(xn4.y);
        a[2] += wv[2][3] * bf2f(xn4.z);
        a[3] += wv[3][3] * bf2f(xn4.w);

        ushort4 o;
        o.x = f2bf(a[0] * fsigmoid(a[0]));
        o.y = f2bf(a[1] * fsigmoid(a[1]));
        o.z = f2bf(a[2] * fsigmoid(a[2]));
        o.w = f2bf(a[3] * fsigmoid(a[3]));
        *reinterpret_cast<ushort4*>(xc + (size_t)r * D + d0) = o;

        win[0] = win[1]; win[1] = win[2]; win[2] = xn4;
    }
}

// ---------------- TM x 128 tile bf16 MFMA GEMM, m97-style simple loop -------
// 256 threads / 4 waves (2x2) / BK=32 / single LDS buffer / plain syncthreads
// + proven 0-conflict XOR swizzle.
// MODE 0: out-GEMM (TM=128). rows identity, W=owh, y = v + ob + x.
// MODE 3: MEGA. bid<1024: gate. bid>=1024: chunk rows (256/batch) x {delta|B|C}.
// MODE 4: TAIL. rows [256,4096)/batch x {delta|B|C}; exit unless need_tail.
template <int TM, int MODE>
__global__ __launch_bounds__(256) void gemm_kernel(
    const unsigned short* __restrict__ A,
    const unsigned short* __restrict__ W,   // MODE 0: owh; MODE 3/4: W4
    const float* __restrict__ bias,         // MODE 0: ob; MODE 3: gb
    const float* __restrict__ pb,
    const float* __restrict__ xres,
    float* __restrict__ outf,
    unsigned short* __restrict__ outh,      // gate
    unsigned short* __restrict__ prm,
    const int* __restrict__ need_tail) {
    constexpr int K  = 1024;
    constexpr int BK = 32;
    constexpr int WM = TM / 2;
    constexpr int MF = WM / 16;
    constexpr int AI = TM / 64;
    __shared__ alignas(16) unsigned short As[TM * BK];
    __shared__ alignas(16) unsigned short Bs[128 * BK];
    const int tid = threadIdx.x;
    const int wave = tid >> 6;
    const int lane = tid & 63;

    const int nwg = (int)gridDim.x;   // all grids % 8 == 0
    const int bid = ((int)blockIdx.x & 7) * (nwg >> 3) + ((int)blockIdx.x >> 3);

    int row0, wrow0;
    if constexpr (MODE == 0) {
        row0 = (bid >> 3) * TM;
        wrow0 = (bid & 7) << 7;
    } else if constexpr (MODE == 3) {
        if (bid < 1024) {                       // gate region
            row0 = (bid >> 3) * 128;
            wrow0 = (bid & 7) << 7;
        } else {                                // chunk region (256 rows/batch)
            const int q = bid - 1024;
            const int rt = q / 24, ct = q % 24; // rt 0..7
            row0 = (rt >> 1) * L + (rt & 1) * 128;
            wrow0 = (ct < 8) ? (3072 + ct * 128)
                  : (ct < 16) ? (1024 + (ct - 8) * 128)
                  : (2048 + (ct - 16) * 128);
        }
    } else {                                    // MODE 4 tail
        const int rt = bid / 24, ct = bid % 24; // rt 0..119
        const int batch = rt / 30;
        if (!need_tail[batch]) return;          // block-uniform exit
        row0 = batch * L + CHUNK + (rt % 30) * 128;
        wrow0 = (ct < 8) ? (3072 + ct * 128)
              : (ct < 16) ? (1024 + (ct - 8) * 128)
              : (2048 + (ct - 16) * 128);
    }

    const int wr = wave >> 1, wc = wave & 1;
    const int lr = lane & 15, kg = lane >> 4;

    f32x4 acc[MF][4];
    #pragma unroll
    for (int i = 0; i < MF; ++i)
        #pragma unroll
        for (int j = 0; j < 4; ++j) acc[i][j] = (f32x4){0.f, 0.f, 0.f, 0.f};

    // staging: linear LDS dest, pre-swizzled global source column (G21)
    const int s_row = tid >> 2;
    const int s_col = 8 * ((tid & 3) ^ ((tid >> 3) & 3));
    const unsigned short* aP = A + (size_t)(row0 + s_row) * K + s_col;
    const unsigned short* bP = W + (size_t)(wrow0 + s_row) * K + s_col;

    // read-side swizzle
    const int acol = (kg * 8) ^ (((lr >> 1) & 3) * 8);
    const int abase = (wr * WM + lr) * BK + acol;
    const int bbase = (wc * 64 + lr) * BK + acol;

    for (int k0 = 0; k0 < K; k0 += BK) {
        #pragma unroll
        for (int i = 0; i < AI; ++i)
            async_lds16(&As[(i * 256 + tid) * 8], aP + (size_t)(i * 64) * K + k0);
        #pragma unroll
        for (int i = 0; i < 2; ++i)
            async_lds16(&Bs[(i * 256 + tid) * 8], bP + (size_t)(i * 64) * K + k0);
        __syncthreads();
        short8 af[MF], bfv[4];
        #pragma unroll
        for (int mi = 0; mi < MF; ++mi)
            af[mi] = *reinterpret_cast<const short8*>(&As[abase + mi * 16 * BK]);
        #pragma unroll
        for (int ni = 0; ni < 4; ++ni)
            bfv[ni] = *reinterpret_cast<const short8*>(&Bs[bbase + ni * 16 * BK]);
        #pragma unroll
        for (int mi = 0; mi < MF; ++mi)
            #pragma unroll
            for (int ni = 0; ni < 4; ++ni)
                acc[mi][ni] = __builtin_amdgcn_mfma_f32_16x16x32_bf16(af[mi], bfv[ni], acc[mi][ni], 0, 0, 0);
        __syncthreads();
    }

    const int r0 = row0 + wr * WM + kg * 4;
    if constexpr (MODE == 0) {
        const int c0 = wrow0 + wc * 64;
        #pragma unroll
        for (int mi = 0; mi < MF; ++mi)
            #pragma unroll
            for (int ni = 0; ni < 4; ++ni) {
                const int col = c0 + ni * 16 + lr;
                #pragma unroll
                for (int j = 0; j < 4; ++j) {
                    const int row = r0 + mi * 16 + j;
                    outf[(size_t)row * 1024 + col] =
                        acc[mi][ni][j] + bias[col] + xres[(size_t)row * 1024 + col];
                }
            }
    } else {
        const int region = wrow0 >> 10;       // 0 gate, 1 B, 2 C, 3 delta
        const int cwb = (wrow0 & 1023) + wc * 64;
        #pragma unroll
        for (int mi = 0; mi < MF; ++mi)
            #pragma unroll
            for (int ni = 0; ni < 4; ++ni) {
                const int cw = cwb + ni * 16 + lr;
                #pragma unroll
                for (int j = 0; j < 4; ++j) {
                    const int row = r0 + mi * 16 + j;
                    const float v = acc[mi][ni][j];
                    if (region == 0) {
                        outh[(size_t)row * 1024 + cw] = f2bf(fsigmoid(v + bias[cw]));
                    } else if (region == 3) {
                        const int idx = (cw >> 6) * 192 + (cw & 63);
                        prm[(size_t)row * NP + idx] = f2bf(fsigmoid(v + pb[idx]));
                    } else if (region == 1) {
                        const int idx = (cw >> 6) * 192 + 64 + (cw & 63);
                        prm[(size_t)row * NP + idx] = f2bf(v + pb[idx]);
                    } else {
                        const int idx = (cw >> 6) * 192 + 128 + (cw & 63);
                        prm[(size_t)row * NP + idx] = f2bf(v + pb[idx]);
                    }
                }
            }
    }
}

// ---------------- prefixA: per-head saturation within CHUNK -> need_tail ----
__global__ __launch_bounds__(64) void prefixA_kernel(const unsigned short* __restrict__ prm,
                                                     int* __restrict__ need_tail) {
    const int bh = blockIdx.x;           // b*16 + h
    const int b = bh >> 4, h = bh & 15;
    const int s = threadIdx.x;
    const unsigned short* base = prm + (size_t)b * L * NP + h * 192 + s;
    float p = 1.0f;
    bool sat = false;
    for (int l = 0; l < CHUNK; l += 8) {
        float dv[8];
        #pragma unroll
        for (int j = 0; j < 8; ++j) dv[j] = bf2f(base[(size_t)(l + j) * NP]);
        #pragma unroll
        for (int j = 0; j < 8; ++j) p = p * dv[j];
        if (__all(p == 0.0f)) { sat = true; break; }
    }
    if (s == 0 && !sat) atomicOr(need_tail + b, 1);
}

// ---------------- selective scan (bf16 params in, bf16 ssm out) -------------
// Writes ssm rows [0, lend) and prefix2[bh] = lend (mix's read bound).
__global__ __launch_bounds__(64) void scan_kernel(const unsigned short* __restrict__ prm,
                                                  const float* __restrict__ state,
                                                  unsigned short* __restrict__ ssm,
                                                  float* __restrict__ hlast,
                                                  int* __restrict__ prefix2) {
    const int bh = blockIdx.x;           // b*16 + h
    const int b = bh >> 4, h = bh & 15;
    const int s = threadIdx.x;           // 0..63
    const unsigned short* base = prm + (size_t)b * L * NP + h * 192 + s;
    unsigned short* ob = ssm + (size_t)b * L * D + h * 64 + s;
    const float h0 = state[(size_t)bh * 64 + s];
    float p = 1.0f, cu = 0.0f;
    bool live = true;
    int lend = 0;
    for (int l = 0; l < L && live; l += 8) {
        float dv[8], bv[8], cv[8];
        #pragma unroll
        for (int j = 0; j < 8; ++j) {
            const unsigned short* pp = base + (size_t)(l + j) * NP;
            dv[j] = bf2f(pp[0]);
            bv[j] = bf2f(pp[64]);
            cv[j] = bf2f(pp[128]);
        }
        #pragma unroll
        for (int j = 0; j < 8; ++j) {
            p = p * dv[j];
            const float u = bv[j] / (p + 1e-8f);
            cu += u;
            const float hh = p * (h0 + cu);
            ob[(size_t)(l + j) * D] = f2bf(cv[j] * hh);
        }
        lend = l + 8;
        if (__all(p == 0.0f)) live = false;
    }
    hlast[(size_t)bh * 64 + s] = live ? p * (h0 + cu) : 0.0f;
    if (s == 0) prefix2[bh] = live ? L : lend;
}

// ---------------- mix: mixed = g*ssm + (1-g)*xn -> bf16 (in place over gate) --
// 8 bf16/thread (128-bit loads, G13); 8-elem group stays in one head slice.
__global__ __launch_bounds__(256) void mix_kernel(unsigned short* __restrict__ gate,
                                                  const unsigned short* __restrict__ ssm,
                                                  const unsigned short* __restrict__ xn,
                                                  const int* __restrict__ prefix2) {
    const size_t i = ((size_t)blockIdx.x * 256 + threadIdx.x) * 8;
    const int row = (int)(i >> 10);
    const int b = row >> 12;
    const int l = row & (L - 1);
    const int h = (int)((i >> 6) & 15);
    short8 g8 = *reinterpret_cast<const short8*>(gate + i);
    short8 x8 = *reinterpret_cast<const short8*>(xn + i);
    short8 s8 = {0,0,0,0,0,0,0,0};
    if (l < prefix2[b * 16 + h]) s8 = *reinterpret_cast<const short8*>(ssm + i);
    short8 o;
    #pragma unroll
    for (int q = 0; q < 8; ++q) {
        const float g = bf2f((unsigned short)g8[q]);
        o[q] = (short)f2bf(g * bf2f((unsigned short)s8[q]) +
                           (1.0f - g) * bf2f((unsigned short)x8[q]));
    }
    *reinterpret_cast<short8*>(gate + i) = o;
}

extern "C" void kernel_launch(void* const* d_in, const int* in_sizes, int n_in,
                              void* d_out, int out_size, void* d_ws, size_t ws_size,
                              hipStream_t stream) {
    const float* x      = (const float*)d_in[0];
    const float* state  = (const float*)d_in[1];
    const float* norm_w = (const float*)d_in[2];
    const float* conv_w = (const float*)d_in[3];
    const float* conv_b = (const float*)d_in[4];
    const float* pw     = (const float*)d_in[5];
    const float* pb     = (const float*)d_in[6];
    const float* gw     = (const float*)d_in[7];
    const float* gb     = (const float*)d_in[8];
    const float* ow     = (const float*)d_in[9];
    const float* ob     = (const float*)d_in[10];

    // ws: gate 32MB | prm 96MB | W4 8MB | owh 2MB | flags
    constexpr size_t NEED = (138ull << 20) + 4096;
    if (ws_size < NEED) return;  // fail loudly instead of faulting

    char* ws = (char*)d_ws;
    unsigned short* gate  = (unsigned short*)(ws);                  // 32 MB (becomes mixed)
    unsigned short* mixed = gate;
    unsigned short* prm   = (unsigned short*)(ws + (32ull  << 20)); // 96 MB
    unsigned short* w4    = (unsigned short*)(ws + (128ull << 20)); // 8 MB
    unsigned short* owh   = (unsigned short*)(ws + (136ull << 20)); // 2 MB
    int*            need_tail = (int*)(ws + (138ull << 20));        // 16 B
    int*            prefix2   = need_tail + NB;                     // 256 B

    // d_out doubles as scratch until the final GEMM overwrites it with y.
    float* y = (float*)d_out;
    float* hlast = y + (size_t)M * D;
    unsigned short* xn  = (unsigned short*)d_out;                   // [0, 32MB)
    unsigned short* xc  = (unsigned short*)((char*)d_out + (32ull << 20)); // [32, 64MB)
    unsigned short* ssm = xc;  // scan overwrites xc region after mega/tail GEMMs

    // fused front: 512 rmsconv blocks + 5120 weight-cast blocks
    front_kernel<<<5632, 256, 0, stream>>>(x, norm_w, conv_w, conv_b,
                                           gw, pw, ow, xn, xc, w4, owh, need_tail);

    // MEGA (BK=32): gate (1024) + chunk delta/B/C (192) = 1216 blocks, all live
    gemm_kernel<128, 3><<<1216, 256, 0, stream>>>(
        xc, w4, gb, pb, nullptr, nullptr, gate, prm, nullptr);

    prefixA_kernel<<<NB * H, 64, 0, stream>>>(prm, need_tail);

    // TAIL (BK=32): rows [256,4096)/batch x delta/B/C; normally all blocks exit
    gemm_kernel<128, 4><<<2880, 256, 0, stream>>>(
        xc, w4, nullptr, pb, nullptr, nullptr, nullptr, prm, need_tail);

    scan_kernel<<<NB * H, 64, 0, stream>>>(prm, state, ssm, hlast, prefix2);

    mix_kernel<<<(M * D) / 2048, 256, 0, stream>>>(gate, ssm, xn, prefix2);

    // out-GEMM: TM=128 -> 128x8 = 1024 blocks
    gemm_kernel<128, 0><<<1024, 256, 0, stream>>>(
        mixed, owh, ob, nullptr, x, y, nullptr, nullptr, nullptr);
}